// Round 5
// baseline (609.210 us; speedup 1.0000x reference)
//
#include <hip/hip_runtime.h>
#include <hip/hip_fp16.h>

#define FDIM 128
#define NGRAPH 256
#define NCLS 10
#define AGG_NODES 8     // nodes per block in k_agg_squash (512 threads = 8 waves)
#define STATS_BLOCKS 256

__device__ __forceinline__ unsigned encf(float f) {
  unsigned b = __float_as_uint(f);
  return (b & 0x80000000u) ? ~b : (b | 0x80000000u);
}
__device__ __forceinline__ float decf(unsigned u) {
  if (u == 0u) return 0.f;  // empty segment -> 0 (matches isfinite->0)
  return (u & 0x80000000u) ? __uint_as_float(u & 0x7FFFFFFFu) : __uint_as_float(~u);
}

// ---------- BN partial sums (blocks 0..255, NO atomics) + deg/graph counts (blocks 256+) ----------
__global__ __launch_bounds__(256) void k_stats_deg(const float* __restrict__ x,
                                                   float* __restrict__ partS,
                                                   float* __restrict__ partQ, int total4,
                                                   const int* __restrict__ src,
                                                   const int* __restrict__ dst,
                                                   int* __restrict__ degcnt,
                                                   const int* __restrict__ batch,
                                                   int* __restrict__ gcnt, int E, int N) {
  int t = threadIdx.x;
  if (blockIdx.x >= STATS_BLOCKS) {
    int e = (blockIdx.x - STATS_BLOCKS) * 256 + t;
    if (e < E) {
      int s = src[e], d = dst[e];
      if (s != d) atomicAdd(degcnt + d, 1);
    }
    if (e < N) atomicAdd(gcnt + batch[e], 1);
    return;
  }
  __shared__ float ss[1024];
  __shared__ float sq[1024];
  float s0 = 0, s1 = 0, s2 = 0, s3 = 0, q0 = 0, q1 = 0, q2 = 0, q3 = 0;
  for (int i = blockIdx.x * 256 + t; i < total4; i += STATS_BLOCKS * 256) {
    float4 v = ((const float4*)x)[i];
    s0 += v.x; q0 += v.x * v.x;
    s1 += v.y; q1 += v.y * v.y;
    s2 += v.z; q2 += v.z * v.z;
    s3 += v.w; q3 += v.w * v.w;
  }
  int fb = (t & 31) * 4, slot = t >> 5;
  ss[slot * 128 + fb + 0] = s0; ss[slot * 128 + fb + 1] = s1;
  ss[slot * 128 + fb + 2] = s2; ss[slot * 128 + fb + 3] = s3;
  sq[slot * 128 + fb + 0] = q0; sq[slot * 128 + fb + 1] = q1;
  sq[slot * 128 + fb + 2] = q2; sq[slot * 128 + fb + 3] = q3;
  __syncthreads();
  if (t < 128) {
    float a = 0, b = 0;
    for (int s = 0; s < 8; s++) { a += ss[s * 128 + t]; b += sq[s * 128 + t]; }
    partS[blockIdx.x * 128 + t] = a;   // plain store — no atomics
    partQ[blockIdx.x * 128 + t] = b;
  }
}

// ---------- finalize dinv / counts / BN affine (reduces the 256 partials) ----------
__global__ __launch_bounds__(256) void k_finalize_pre(const int* __restrict__ degcnt,
                                                      float* __restrict__ dinv,
                                                      const int* __restrict__ gcnt,
                                                      float* __restrict__ countsf,
                                                      const float* __restrict__ partS,
                                                      const float* __restrict__ partQ,
                                                      const float* __restrict__ gamma,
                                                      const float* __restrict__ beta,
                                                      float* __restrict__ aff_a,
                                                      float* __restrict__ aff_b, int N) {
  int i = blockIdx.x * 256 + threadIdx.x;
  if (i < N) dinv[i] = rsqrtf(1.0f + (float)degcnt[i]);
  if (i < NGRAPH) countsf[i] = fmaxf((float)gcnt[i], 1.0f);
  if (i < FDIM) {
    float a = 0.f, b = 0.f;
    for (int bk = 0; bk < STATS_BLOCKS; bk++) {
      a += partS[bk * 128 + i];
      b += partQ[bk * 128 + i];
    }
    float invN = 1.0f / (float)N;
    float mu = a * invN;
    float var = b * invN - mu * mu;
    float inv = rsqrtf(var + 1e-5f);
    float ga = gamma[i] * inv;
    aff_a[i] = ga;
    aff_b[i] = beta[i] - mu * ga;
  }
}

// ---------- scan (3-kernel exclusive prefix sum over degcnt) ----------
__global__ __launch_bounds__(256) void k_scan1(const int* __restrict__ degcnt,
                                               int* __restrict__ incl,
                                               int* __restrict__ bsum, int N) {
  __shared__ int s[256];
  int t = threadIdx.x;
  int i = blockIdx.x * 256 + t;
  int v = (i < N) ? degcnt[i] : 0;
  s[t] = v;
  __syncthreads();
  for (int off = 1; off < 256; off <<= 1) {
    int add = (t >= off) ? s[t - off] : 0;
    __syncthreads();
    s[t] += add;
    __syncthreads();
  }
  if (i < N) incl[i] = s[t];
  if (t == 255) bsum[blockIdx.x] = s[255];
}

__global__ __launch_bounds__(256) void k_scan2(int* __restrict__ bsum, int nb) {
  __shared__ int s[256];
  int t = threadIdx.x;
  int v = (t < nb) ? bsum[t] : 0;
  s[t] = v;
  __syncthreads();
  for (int off = 1; off < 256; off <<= 1) {
    int add = (t >= off) ? s[t - off] : 0;
    __syncthreads();
    s[t] += add;
    __syncthreads();
  }
  if (t < nb) bsum[t] = s[t] - v;  // exclusive
}

__global__ __launch_bounds__(256) void k_scan3(const int* __restrict__ incl,
                                               const int* __restrict__ degcnt,
                                               const int* __restrict__ bsum,
                                               int* __restrict__ row_start, int N) {
  int i = blockIdx.x * 256 + threadIdx.x;
  if (i < N) row_start[i] = incl[i] - degcnt[i] + bsum[blockIdx.x];
}

// ---------- fill CSR: packed (src, dinv[src]*dinv[dst]) per edge ----------
__global__ __launch_bounds__(256) void k_csr_fill(const int* __restrict__ src,
                                                  const int* __restrict__ dst,
                                                  const int* __restrict__ row_start,
                                                  int* __restrict__ cursor,
                                                  const float* __restrict__ dinv,
                                                  int2* __restrict__ ew, int E) {
  int e = blockIdx.x * 256 + threadIdx.x;
  if (e < E) {
    int s = src[e], d = dst[e];
    if (s != d) {
      int p = row_start[d] + atomicAdd(cursor + d, 1);
      ew[p] = make_int2(s, __float_as_int(dinv[s] * dinv[d]));
    }
  }
}

// ---------- GEMM: H = X @ W  (N x 128 @ 128 x 128), W in LDS; H stored fp16 ----------
template <int AFFINE>
__global__ __launch_bounds__(256) void k_gemm(const float* __restrict__ Xin,
                                              const float* __restrict__ W,
                                              const float* __restrict__ aff_a,
                                              const float* __restrict__ aff_b,
                                              __half* __restrict__ Hout, int N) {
  __shared__ float sW[128 * 128];
  __shared__ float sA[128];
  __shared__ float sB[128];
  int t = threadIdx.x;
#pragma unroll
  for (int i = 0; i < 16; i++) {
    int idx = t * 4 + i * 1024;
    *(float4*)(sW + idx) = *(const float4*)(W + idx);
  }
  if (AFFINE && t < 128) { sA[t] = aff_a[t]; sB[t] = aff_b[t]; }
  __syncthreads();
  int tx = t & 31, ty = t >> 5;
  int nodeBase = blockIdx.x * 64 + ty * 8;
  if (nodeBase >= N) return;  // after the only __syncthreads
  int nidx[8];
#pragma unroll
  for (int i = 0; i < 8; i++) nidx[i] = min(nodeBase + i, N - 1);
  float acc[8][4];
#pragma unroll
  for (int i = 0; i < 8; i++) { acc[i][0] = acc[i][1] = acc[i][2] = acc[i][3] = 0.f; }
#pragma unroll 2
  for (int k = 0; k < 128; k += 4) {
    float4 b0 = *(const float4*)(sW + (k + 0) * 128 + tx * 4);
    float4 b1 = *(const float4*)(sW + (k + 1) * 128 + tx * 4);
    float4 b2 = *(const float4*)(sW + (k + 2) * 128 + tx * 4);
    float4 b3 = *(const float4*)(sW + (k + 3) * 128 + tx * 4);
    float4 va, vb;
    if (AFFINE) { va = *(const float4*)(sA + k); vb = *(const float4*)(sB + k); }
#pragma unroll
    for (int i = 0; i < 8; i++) {
      float4 a = *(const float4*)(Xin + (long)nidx[i] * 128 + k);
      if (AFFINE) {
        a.x = fmaf(a.x, va.x, vb.x);
        a.y = fmaf(a.y, va.y, vb.y);
        a.z = fmaf(a.z, va.z, vb.z);
        a.w = fmaf(a.w, va.w, vb.w);
      }
      acc[i][0] = fmaf(a.w, b3.x, fmaf(a.z, b2.x, fmaf(a.y, b1.x, fmaf(a.x, b0.x, acc[i][0]))));
      acc[i][1] = fmaf(a.w, b3.y, fmaf(a.z, b2.y, fmaf(a.y, b1.y, fmaf(a.x, b0.y, acc[i][1]))));
      acc[i][2] = fmaf(a.w, b3.z, fmaf(a.z, b2.z, fmaf(a.y, b1.z, fmaf(a.x, b0.z, acc[i][2]))));
      acc[i][3] = fmaf(a.w, b3.w, fmaf(a.z, b2.w, fmaf(a.y, b1.w, fmaf(a.x, b0.w, acc[i][3]))));
    }
  }
#pragma unroll
  for (int i = 0; i < 8; i++) {
    int node = nodeBase + i;
    if (node < N) {
      __half2 p0 = __floats2half2_rn(acc[i][0], acc[i][1]);
      __half2 p1 = __floats2half2_rn(acc[i][2], acc[i][3]);
      uint2 st;
      st.x = *(unsigned*)&p0;
      st.y = *(unsigned*)&p1;
      *(uint2*)(Hout + (size_t)node * 128 + tx * 4) = st;
    }
  }
}

// ---------- fused: CSR aggregate + bias + squash + attention + graph scatter ----------
// One wave per dst node, HALF-WAVE edge split: lanes 0-31 take even edges,
// lanes 32-63 odd edges; each half-wave loads a full 256B fp16 row via 8B/lane.
// 4 slots x 2 edges = 8 gathers in flight per wave. fp32 accumulate; halves
// combined with one shfl_xor(32). Lane q=(l&31) owns features 4q..4q+3.
__global__ __launch_bounds__(512) void k_agg_squash(const __half2* __restrict__ H,
                                                    const int* __restrict__ row_start,
                                                    const int* __restrict__ degcnt,
                                                    const int2* __restrict__ ew,
                                                    const float* __restrict__ bias,
                                                    const float* __restrict__ watt,
                                                    const int* __restrict__ batch,
                                                    const float* __restrict__ dinv,
                                                    float* __restrict__ X,
                                                    float* __restrict__ wsum,
                                                    float* __restrict__ msum,
                                                    unsigned* __restrict__ maxenc, int N) {
  __shared__ float l_ws[128];
  __shared__ float l_ms[128];
  __shared__ unsigned l_mx[128];
  int t = threadIdx.x;
  if (t < 128) { l_ws[t] = 0.f; l_ms[t] = 0.f; l_mx[t] = 0u; }
  __syncthreads();

  int wv = t >> 6, l = t & 63;
  int hw = l >> 5, q = l & 31;
  int node = blockIdx.x * AGG_NODES + wv;
  int g0 = batch[blockIdx.x * AGG_NODES];
  bool valid = node < N;
  float x0 = 0.f, x1 = 0.f, x2 = 0.f, x3 = 0.f, att = 0.f;
  int g = g0;
  if (valid) {
    int st = row_start[node], cnt = degcnt[node];
    float a0 = 0.f, a1 = 0.f, a2 = 0.f, a3 = 0.f;
    int j = 0;
    for (; j + 8 <= cnt; j += 8) {
      int2 e0 = ew[st + j + 0 + hw];
      int2 e1 = ew[st + j + 2 + hw];
      int2 e2 = ew[st + j + 4 + hw];
      int2 e3 = ew[st + j + 6 + hw];
      uint2 r0 = *(const uint2*)(H + (size_t)e0.x * 64 + q * 2);
      uint2 r1 = *(const uint2*)(H + (size_t)e1.x * 64 + q * 2);
      uint2 r2 = *(const uint2*)(H + (size_t)e2.x * 64 + q * 2);
      uint2 r3 = *(const uint2*)(H + (size_t)e3.x * 64 + q * 2);
      float w0 = __int_as_float(e0.y), w1 = __int_as_float(e1.y);
      float w2 = __int_as_float(e2.y), w3 = __int_as_float(e3.y);
      float2 lo, hi;
      lo = __half22float2(*(const __half2*)&r0.x); hi = __half22float2(*(const __half2*)&r0.y);
      a0 = fmaf(w0, lo.x, a0); a1 = fmaf(w0, lo.y, a1);
      a2 = fmaf(w0, hi.x, a2); a3 = fmaf(w0, hi.y, a3);
      lo = __half22float2(*(const __half2*)&r1.x); hi = __half22float2(*(const __half2*)&r1.y);
      a0 = fmaf(w1, lo.x, a0); a1 = fmaf(w1, lo.y, a1);
      a2 = fmaf(w1, hi.x, a2); a3 = fmaf(w1, hi.y, a3);
      lo = __half22float2(*(const __half2*)&r2.x); hi = __half22float2(*(const __half2*)&r2.y);
      a0 = fmaf(w2, lo.x, a0); a1 = fmaf(w2, lo.y, a1);
      a2 = fmaf(w2, hi.x, a2); a3 = fmaf(w2, hi.y, a3);
      lo = __half22float2(*(const __half2*)&r3.x); hi = __half22float2(*(const __half2*)&r3.y);
      a0 = fmaf(w3, lo.x, a0); a1 = fmaf(w3, lo.y, a1);
      a2 = fmaf(w3, hi.x, a2); a3 = fmaf(w3, hi.y, a3);
    }
    for (; j < cnt; j += 2) {
      int eidx = j + hw;
      bool on = eidx < cnt;
      int2 e = on ? ew[st + eidx] : make_int2(0, 0);
      float wgt = on ? __int_as_float(e.y) : 0.f;
      int sidx = on ? e.x : 0;
      uint2 r = *(const uint2*)(H + (size_t)sidx * 64 + q * 2);
      float2 lo = __half22float2(*(const __half2*)&r.x);
      float2 hi = __half22float2(*(const __half2*)&r.y);
      a0 = fmaf(wgt, lo.x, a0); a1 = fmaf(wgt, lo.y, a1);
      a2 = fmaf(wgt, hi.x, a2); a3 = fmaf(wgt, hi.y, a3);
    }
    // combine the two half-waves' edge partials
    a0 += __shfl_xor(a0, 32); a1 += __shfl_xor(a1, 32);
    a2 += __shfl_xor(a2, 32); a3 += __shfl_xor(a3, 32);
    // self loop + bias (computed identically in both halves)
    float dn = dinv[node], sl = dn * dn;
    uint2 hs = *(const uint2*)(H + (size_t)node * 64 + q * 2);
    float2 lo = __half22float2(*(const __half2*)&hs.x);
    float2 hi = __half22float2(*(const __half2*)&hs.y);
    float4 bb = *(const float4*)(bias + q * 4);
    a0 = fmaf(sl, lo.x, a0 + bb.x); a1 = fmaf(sl, lo.y, a1 + bb.y);
    a2 = fmaf(sl, hi.x, a2 + bb.z); a3 = fmaf(sl, hi.y, a3 + bb.w);
    // squash (reduce within 32-lane half-wave: it holds all 128 features)
    float p = a0 * a0 + a1 * a1 + a2 * a2 + a3 * a3;
#pragma unroll
    for (int m = 1; m < 32; m <<= 1) p += __shfl_xor(p, m);
    float factor = (p / (1.0f + p)) * rsqrtf(p + 1e-8f);
    x0 = a0 * factor; x1 = a1 * factor; x2 = a2 * factor; x3 = a3 * factor;
    if (hw == 0)
      *(float4*)(X + (size_t)node * 128 + q * 4) = make_float4(x0, x1, x2, x3);
    float4 wa = *(const float4*)(watt + q * 4);
    att = x0 * wa.x + x1 * wa.y + x2 * wa.z + x3 * wa.w;
#pragma unroll
    for (int m = 1; m < 32; m <<= 1) att += __shfl_xor(att, m);
    g = batch[node];
  }
  if (valid && hw == 0) {
    int fb = q * 4;
    if (g == g0) {
      atomicAdd(&l_ws[fb + 0], att * x0); atomicAdd(&l_ws[fb + 1], att * x1);
      atomicAdd(&l_ws[fb + 2], att * x2); atomicAdd(&l_ws[fb + 3], att * x3);
      atomicAdd(&l_ms[fb + 0], x0); atomicAdd(&l_ms[fb + 1], x1);
      atomicAdd(&l_ms[fb + 2], x2); atomicAdd(&l_ms[fb + 3], x3);
      atomicMax(&l_mx[fb + 0], encf(x0)); atomicMax(&l_mx[fb + 1], encf(x1));
      atomicMax(&l_mx[fb + 2], encf(x2)); atomicMax(&l_mx[fb + 3], encf(x3));
    } else {  // rare: graph boundary inside block
      int base = g * 128 + fb;
      atomicAdd(wsum + base + 0, att * x0); atomicAdd(wsum + base + 1, att * x1);
      atomicAdd(wsum + base + 2, att * x2); atomicAdd(wsum + base + 3, att * x3);
      atomicAdd(msum + base + 0, x0); atomicAdd(msum + base + 1, x1);
      atomicAdd(msum + base + 2, x2); atomicAdd(msum + base + 3, x3);
      atomicMax(maxenc + base + 0, encf(x0)); atomicMax(maxenc + base + 1, encf(x1));
      atomicMax(maxenc + base + 2, encf(x2)); atomicMax(maxenc + base + 3, encf(x3));
    }
  }
  __syncthreads();
  if (t < 128) {
    int base = g0 * 128 + t;
    atomicAdd(wsum + base, l_ws[t]);
    atomicAdd(msum + base, l_ms[t]);
    unsigned u = l_mx[t];
    if (u) atomicMax(maxenc + base, u);
  }
}

// ---------- MLP head + log_softmax, one block per graph ----------
__global__ __launch_bounds__(128) void k_head(const float* __restrict__ wsum,
                                              const float* __restrict__ msum,
                                              const unsigned* __restrict__ maxenc,
                                              const float* __restrict__ countsf,
                                              const float* __restrict__ l1w,
                                              const float* __restrict__ l1b,
                                              const float* __restrict__ l2w,
                                              const float* __restrict__ l2b,
                                              float* __restrict__ out) {
  int g = blockIdx.x, t = threadIdx.x;
  __shared__ float rep[384];
  __shared__ float h1[128];
  __shared__ float lg[NCLS];
  float invc = 1.0f / countsf[g];
  rep[t] = wsum[g * 128 + t];
  rep[128 + t] = msum[g * 128 + t] * invc;
  rep[256 + t] = decf(maxenc[g * 128 + t]) +
                 decf(maxenc[NGRAPH * 128 + g * 128 + t]) +
                 decf(maxenc[2 * NGRAPH * 128 + g * 128 + t]);
  __syncthreads();
  float acc = l1b[t];
  for (int k = 0; k < 384; k++) acc = fmaf(rep[k], l1w[k * 128 + t], acc);
  h1[t] = fmaxf(acc, 0.f);
  __syncthreads();
  if (t < NCLS) {
    float a = l2b[t];
    for (int j = 0; j < 128; j++) a = fmaf(h1[j], l2w[j * NCLS + t], a);
    lg[t] = a;
  }
  __syncthreads();
  if (t < NCLS) {
    float m = lg[0];
    for (int c = 1; c < NCLS; c++) m = fmaxf(m, lg[c]);
    float s = 0.f;
    for (int c = 0; c < NCLS; c++) s += expf(lg[c] - m);
    out[g * NCLS + t] = lg[t] - m - logf(s);
  }
}

extern "C" void kernel_launch(void* const* d_in, const int* in_sizes, int n_in,
                              void* d_out, int out_size, void* d_ws, size_t ws_size,
                              hipStream_t stream) {
  const float* x      = (const float*)d_in[0];
  const int* edge     = (const int*)d_in[1];
  const int* batch    = (const int*)d_in[2];
  const float* gamma  = (const float*)d_in[3];
  const float* beta   = (const float*)d_in[4];
  const float* gcn_w  = (const float*)d_in[5];
  const float* gcn_b  = (const float*)d_in[6];
  const float* w_att  = (const float*)d_in[7];
  const float* l1w    = (const float*)d_in[8];
  const float* l1b    = (const float*)d_in[9];
  const float* l2w    = (const float*)d_in[10];
  const float* l2b    = (const float*)d_in[11];
  float* out          = (float*)d_out;

  const int N = in_sizes[0] / FDIM;   // 50000
  const int E = in_sizes[1] / 2;      // 640000
  const int* esrc = edge;
  const int* edst = edge + E;

  char* w = (char*)d_ws;
  size_t off = 0;
  auto alloc = [&](size_t bytes) {
    void* p = (void*)(w + off);
    off += (bytes + 1023) & ~(size_t)1023;
    return p;
  };
  float* X  = (float*)alloc((size_t)N * FDIM * 4);
  __half* H = (__half*)alloc((size_t)N * FDIM * 2);
  // zero zone start
  size_t zoff = off;
  int* degcnt      = (int*)alloc((size_t)N * 4);
  int* cursor      = (int*)alloc((size_t)N * 4);
  int* gcnt        = (int*)alloc(NGRAPH * 4);
  float* wsum      = (float*)alloc(NGRAPH * FDIM * 4);
  float* msum      = (float*)alloc(NGRAPH * FDIM * 4);
  unsigned* maxenc = (unsigned*)alloc((size_t)3 * NGRAPH * FDIM * 4);  // per-layer
  size_t zbytes = off - zoff;
  // non-zeroed
  float* partS    = (float*)alloc((size_t)STATS_BLOCKS * FDIM * 4);
  float* partQ    = (float*)alloc((size_t)STATS_BLOCKS * FDIM * 4);
  float* dinv     = (float*)alloc((size_t)N * 4);
  float* countsf  = (float*)alloc(NGRAPH * 4);
  float* aff_a    = (float*)alloc(FDIM * 4);
  float* aff_b    = (float*)alloc(FDIM * 4);
  int* incl       = (int*)alloc((size_t)N * 4);
  int* bsum       = (int*)alloc(1024);
  int* row_start  = (int*)alloc((size_t)N * 4);
  int2* ew        = (int2*)alloc((size_t)E * 8);
  (void)ws_size; (void)n_in; (void)out_size;

  hipMemsetAsync(w + zoff, 0, zbytes, stream);

  const int nbN = (N + 255) / 256;
  const int nbE = (E + 255) / 256;
  const int total4 = N * FDIM / 4;

  k_stats_deg<<<STATS_BLOCKS + nbE, 256, 0, stream>>>(x, partS, partQ, total4, esrc,
                                                      edst, degcnt, batch, gcnt, E, N);
  k_finalize_pre<<<nbN, 256, 0, stream>>>(degcnt, dinv, gcnt, countsf, partS, partQ,
                                          gamma, beta, aff_a, aff_b, N);
  k_scan1<<<nbN, 256, 0, stream>>>(degcnt, incl, bsum, N);
  k_scan2<<<1, 256, 0, stream>>>(bsum, nbN);
  k_scan3<<<nbN, 256, 0, stream>>>(incl, degcnt, bsum, row_start, N);
  k_csr_fill<<<nbE, 256, 0, stream>>>(esrc, edst, row_start, cursor, dinv, ew, E);

  const int gemmBlocks = (N + 63) / 64;
  const int aggBlocks = (N + AGG_NODES - 1) / AGG_NODES;
  for (int layer = 0; layer < 3; layer++) {
    if (layer == 0)
      k_gemm<1><<<gemmBlocks, 256, 0, stream>>>(x, gcn_w, aff_a, aff_b, H, N);
    else
      k_gemm<0><<<gemmBlocks, 256, 0, stream>>>(X, gcn_w + (size_t)layer * FDIM * FDIM,
                                                aff_a, aff_b, H, N);
    k_agg_squash<<<aggBlocks, 512, 0, stream>>>((const __half2*)H, row_start, degcnt, ew,
                                                gcn_b + layer * FDIM,
                                                w_att + layer * FDIM, batch, dinv, X,
                                                wsum, msum,
                                                maxenc + (size_t)layer * NGRAPH * FDIM, N);
  }
  k_head<<<NGRAPH, 128, 0, stream>>>(wsum, msum, maxenc, countsf, l1w, l1b, l2w, l2b, out);
}

// Round 6
// 537.762 us; speedup vs baseline: 1.1329x; 1.1329x over previous
//
#include <hip/hip_runtime.h>
#include <hip/hip_fp16.h>

#define FDIM 128
#define NGRAPH 256
#define NCLS 10
#define AGG_NODES 8     // nodes per block in k_agg_squash (512 threads = 8 waves)
#define STATS_BLOCKS 256
#define CSTRIDE 16      // ints per counter slot (one 64B cache line) — kills per-line atomic serialization

__device__ __forceinline__ unsigned encf(float f) {
  unsigned b = __float_as_uint(f);
  return (b & 0x80000000u) ? ~b : (b | 0x80000000u);
}
__device__ __forceinline__ float decf(unsigned u) {
  if (u == 0u) return 0.f;  // empty segment -> 0 (matches isfinite->0)
  return (u & 0x80000000u) ? __uint_as_float(u & 0x7FFFFFFFu) : __uint_as_float(~u);
}

// ---------- BN partial sums (blocks 0..255, no atomics) + degree (spread atomics)
// ---------- + graph segment boundaries from sorted batch (blocks 256+) ----------
__global__ __launch_bounds__(256) void k_stats_deg(const float* __restrict__ x,
                                                   float* __restrict__ partS,
                                                   float* __restrict__ partQ, int total4,
                                                   const int* __restrict__ src,
                                                   const int* __restrict__ dst,
                                                   int* __restrict__ degcnt,
                                                   const int* __restrict__ batch,
                                                   int* __restrict__ gstart,
                                                   int* __restrict__ gend, int E, int N) {
  int t = threadIdx.x;
  if (blockIdx.x >= STATS_BLOCKS) {
    int e = (blockIdx.x - STATS_BLOCKS) * 256 + t;
    if (e < E) {
      int s = src[e], d = dst[e];
      if (s != d) atomicAdd(degcnt + (size_t)d * CSTRIDE, 1);
    }
    if (e < N) {
      int b = batch[e];
      if (e == 0 || batch[e - 1] != b) gstart[b] = e;       // plain stores, ~256 total
      if (e == N - 1) gend[b] = N;
      else if (batch[e + 1] != b) gend[b] = e + 1;
    }
    return;
  }
  __shared__ float ss[1024];
  __shared__ float sq[1024];
  float s0 = 0, s1 = 0, s2 = 0, s3 = 0, q0 = 0, q1 = 0, q2 = 0, q3 = 0;
  for (int i = blockIdx.x * 256 + t; i < total4; i += STATS_BLOCKS * 256) {
    float4 v = ((const float4*)x)[i];
    s0 += v.x; q0 += v.x * v.x;
    s1 += v.y; q1 += v.y * v.y;
    s2 += v.z; q2 += v.z * v.z;
    s3 += v.w; q3 += v.w * v.w;
  }
  int fb = (t & 31) * 4, slot = t >> 5;
  ss[slot * 128 + fb + 0] = s0; ss[slot * 128 + fb + 1] = s1;
  ss[slot * 128 + fb + 2] = s2; ss[slot * 128 + fb + 3] = s3;
  sq[slot * 128 + fb + 0] = q0; sq[slot * 128 + fb + 1] = q1;
  sq[slot * 128 + fb + 2] = q2; sq[slot * 128 + fb + 3] = q3;
  __syncthreads();
  if (t < 128) {
    float a = 0, b = 0;
    for (int s = 0; s < 8; s++) { a += ss[s * 128 + t]; b += sq[s * 128 + t]; }
    partS[blockIdx.x * 128 + t] = a;
    partQ[blockIdx.x * 128 + t] = b;
  }
}

// ---------- finalize: dinv + repack degcnt + counts from boundaries + BN affine ----------
__global__ __launch_bounds__(256) void k_finalize_pre(const int* __restrict__ degcnt,
                                                      int* __restrict__ deg_packed,
                                                      float* __restrict__ dinv,
                                                      const int* __restrict__ gstart,
                                                      const int* __restrict__ gend,
                                                      float* __restrict__ countsf,
                                                      const float* __restrict__ partS,
                                                      const float* __restrict__ partQ,
                                                      const float* __restrict__ gamma,
                                                      const float* __restrict__ beta,
                                                      float* __restrict__ aff_a,
                                                      float* __restrict__ aff_b, int N) {
  int i = blockIdx.x * 256 + threadIdx.x;
  if (i < N) {
    int d = degcnt[(size_t)i * CSTRIDE];
    deg_packed[i] = d;
    dinv[i] = rsqrtf(1.0f + (float)d);
  }
  if (i < NGRAPH) countsf[i] = fmaxf((float)(gend[i] - gstart[i]), 1.0f);
  if (i < FDIM) {
    float a = 0.f, b = 0.f;
    for (int bk = 0; bk < STATS_BLOCKS; bk++) {
      a += partS[bk * 128 + i];
      b += partQ[bk * 128 + i];
    }
    float invN = 1.0f / (float)N;
    float mu = a * invN;
    float var = b * invN - mu * mu;
    float inv = rsqrtf(var + 1e-5f);
    float ga = gamma[i] * inv;
    aff_a[i] = ga;
    aff_b[i] = beta[i] - mu * ga;
  }
}

// ---------- scan (3-kernel exclusive prefix sum over deg_packed) ----------
__global__ __launch_bounds__(256) void k_scan1(const int* __restrict__ deg,
                                               int* __restrict__ incl,
                                               int* __restrict__ bsum, int N) {
  __shared__ int s[256];
  int t = threadIdx.x;
  int i = blockIdx.x * 256 + t;
  int v = (i < N) ? deg[i] : 0;
  s[t] = v;
  __syncthreads();
  for (int off = 1; off < 256; off <<= 1) {
    int add = (t >= off) ? s[t - off] : 0;
    __syncthreads();
    s[t] += add;
    __syncthreads();
  }
  if (i < N) incl[i] = s[t];
  if (t == 255) bsum[blockIdx.x] = s[255];
}

__global__ __launch_bounds__(256) void k_scan2(int* __restrict__ bsum, int nb) {
  __shared__ int s[256];
  int t = threadIdx.x;
  int v = (t < nb) ? bsum[t] : 0;
  s[t] = v;
  __syncthreads();
  for (int off = 1; off < 256; off <<= 1) {
    int add = (t >= off) ? s[t - off] : 0;
    __syncthreads();
    s[t] += add;
    __syncthreads();
  }
  if (t < nb) bsum[t] = s[t] - v;  // exclusive
}

__global__ __launch_bounds__(256) void k_scan3(const int* __restrict__ incl,
                                               const int* __restrict__ deg,
                                               const int* __restrict__ bsum,
                                               int* __restrict__ row_start, int N) {
  int i = blockIdx.x * 256 + threadIdx.x;
  if (i < N) row_start[i] = incl[i] - deg[i] + bsum[blockIdx.x];
}

// ---------- fill CSR: packed (src, dinv[src]*dinv[dst]); cursor spread 1/line ----------
__global__ __launch_bounds__(256) void k_csr_fill(const int* __restrict__ src,
                                                  const int* __restrict__ dst,
                                                  const int* __restrict__ row_start,
                                                  int* __restrict__ cursor,
                                                  const float* __restrict__ dinv,
                                                  int2* __restrict__ ew, int E) {
  int e = blockIdx.x * 256 + threadIdx.x;
  if (e < E) {
    int s = src[e], d = dst[e];
    if (s != d) {
      int p = row_start[d] + atomicAdd(cursor + (size_t)d * CSTRIDE, 1);
      ew[p] = make_int2(s, __float_as_int(dinv[s] * dinv[d]));
    }
  }
}

// ---------- GEMM: H = X @ W  (N x 128 @ 128 x 128), W in LDS; H stored fp16 ----------
template <int AFFINE>
__global__ __launch_bounds__(256) void k_gemm(const float* __restrict__ Xin,
                                              const float* __restrict__ W,
                                              const float* __restrict__ aff_a,
                                              const float* __restrict__ aff_b,
                                              __half* __restrict__ Hout, int N) {
  __shared__ float sW[128 * 128];
  __shared__ float sA[128];
  __shared__ float sB[128];
  int t = threadIdx.x;
#pragma unroll
  for (int i = 0; i < 16; i++) {
    int idx = t * 4 + i * 1024;
    *(float4*)(sW + idx) = *(const float4*)(W + idx);
  }
  if (AFFINE && t < 128) { sA[t] = aff_a[t]; sB[t] = aff_b[t]; }
  __syncthreads();
  int tx = t & 31, ty = t >> 5;
  int nodeBase = blockIdx.x * 64 + ty * 8;
  if (nodeBase >= N) return;  // after the only __syncthreads
  int nidx[8];
#pragma unroll
  for (int i = 0; i < 8; i++) nidx[i] = min(nodeBase + i, N - 1);
  float acc[8][4];
#pragma unroll
  for (int i = 0; i < 8; i++) { acc[i][0] = acc[i][1] = acc[i][2] = acc[i][3] = 0.f; }
#pragma unroll 2
  for (int k = 0; k < 128; k += 4) {
    float4 b0 = *(const float4*)(sW + (k + 0) * 128 + tx * 4);
    float4 b1 = *(const float4*)(sW + (k + 1) * 128 + tx * 4);
    float4 b2 = *(const float4*)(sW + (k + 2) * 128 + tx * 4);
    float4 b3 = *(const float4*)(sW + (k + 3) * 128 + tx * 4);
    float4 va, vb;
    if (AFFINE) { va = *(const float4*)(sA + k); vb = *(const float4*)(sB + k); }
#pragma unroll
    for (int i = 0; i < 8; i++) {
      float4 a = *(const float4*)(Xin + (long)nidx[i] * 128 + k);
      if (AFFINE) {
        a.x = fmaf(a.x, va.x, vb.x);
        a.y = fmaf(a.y, va.y, vb.y);
        a.z = fmaf(a.z, va.z, vb.z);
        a.w = fmaf(a.w, va.w, vb.w);
      }
      acc[i][0] = fmaf(a.w, b3.x, fmaf(a.z, b2.x, fmaf(a.y, b1.x, fmaf(a.x, b0.x, acc[i][0]))));
      acc[i][1] = fmaf(a.w, b3.y, fmaf(a.z, b2.y, fmaf(a.y, b1.y, fmaf(a.x, b0.y, acc[i][1]))));
      acc[i][2] = fmaf(a.w, b3.z, fmaf(a.z, b2.z, fmaf(a.y, b1.z, fmaf(a.x, b0.z, acc[i][2]))));
      acc[i][3] = fmaf(a.w, b3.w, fmaf(a.z, b2.w, fmaf(a.y, b1.w, fmaf(a.x, b0.w, acc[i][3]))));
    }
  }
#pragma unroll
  for (int i = 0; i < 8; i++) {
    int node = nodeBase + i;
    if (node < N) {
      __half2 p0 = __floats2half2_rn(acc[i][0], acc[i][1]);
      __half2 p1 = __floats2half2_rn(acc[i][2], acc[i][3]);
      uint2 st;
      st.x = *(unsigned*)&p0;
      st.y = *(unsigned*)&p1;
      *(uint2*)(Hout + (size_t)node * 128 + tx * 4) = st;
    }
  }
}

// ---------- fused: CSR aggregate + bias + squash + attention + graph scatter ----------
// One wave per dst node; lane l owns features 2l,2l+1 (one half2 = 4B per lane).
// Edge loop unrolled x4 (independent gathers in flight); fp32 accumulate.  [R4 form]
__global__ __launch_bounds__(512) void k_agg_squash(const __half2* __restrict__ H,
                                                    const int* __restrict__ row_start,
                                                    const int* __restrict__ deg,
                                                    const int2* __restrict__ ew,
                                                    const float* __restrict__ bias,
                                                    const float* __restrict__ watt,
                                                    const int* __restrict__ batch,
                                                    const float* __restrict__ dinv,
                                                    float* __restrict__ X,
                                                    float* __restrict__ wsum,
                                                    float* __restrict__ msum,
                                                    unsigned* __restrict__ maxenc, int N) {
  __shared__ float l_ws[128];
  __shared__ float l_ms[128];
  __shared__ unsigned l_mx[128];
  int t = threadIdx.x;
  if (t < 128) { l_ws[t] = 0.f; l_ms[t] = 0.f; l_mx[t] = 0u; }
  __syncthreads();

  int wv = t >> 6, l = t & 63;
  int node = blockIdx.x * AGG_NODES + wv;
  int g0 = batch[blockIdx.x * AGG_NODES];
  bool valid = node < N;
  float2 xv = make_float2(0.f, 0.f);
  float att = 0.f;
  int g = g0;
  if (valid) {
    float dn = dinv[node];
    float2 h0 = __half22float2(H[(size_t)node * 64 + l]);
    float2 bb = *(const float2*)(bias + 2 * l);
    float sl = dn * dn;
    float a0x = fmaf(sl, h0.x, bb.x), a0y = fmaf(sl, h0.y, bb.y);
    float a1x = 0.f, a1y = 0.f, a2x = 0.f, a2y = 0.f, a3x = 0.f, a3y = 0.f;
    int st = row_start[node], cnt = deg[node];
    int j = 0;
    for (; j + 4 <= cnt; j += 4) {
      int2 e0 = ew[st + j + 0];
      int2 e1 = ew[st + j + 1];
      int2 e2 = ew[st + j + 2];
      int2 e3 = ew[st + j + 3];
      float2 r0 = __half22float2(H[(size_t)e0.x * 64 + l]);
      float2 r1 = __half22float2(H[(size_t)e1.x * 64 + l]);
      float2 r2 = __half22float2(H[(size_t)e2.x * 64 + l]);
      float2 r3 = __half22float2(H[(size_t)e3.x * 64 + l]);
      float w0 = __int_as_float(e0.y), w1 = __int_as_float(e1.y);
      float w2 = __int_as_float(e2.y), w3 = __int_as_float(e3.y);
      a0x = fmaf(w0, r0.x, a0x); a0y = fmaf(w0, r0.y, a0y);
      a1x = fmaf(w1, r1.x, a1x); a1y = fmaf(w1, r1.y, a1y);
      a2x = fmaf(w2, r2.x, a2x); a2y = fmaf(w2, r2.y, a2y);
      a3x = fmaf(w3, r3.x, a3x); a3y = fmaf(w3, r3.y, a3y);
    }
    for (; j < cnt; j++) {
      int2 e = ew[st + j];
      float2 r = __half22float2(H[(size_t)e.x * 64 + l]);
      float wgt = __int_as_float(e.y);
      a0x = fmaf(wgt, r.x, a0x); a0y = fmaf(wgt, r.y, a0y);
    }
    float ax = (a0x + a1x) + (a2x + a3x);
    float ay = (a0y + a1y) + (a2y + a3y);
    float p = ax * ax + ay * ay;
#pragma unroll
    for (int m = 1; m < 64; m <<= 1) p += __shfl_xor(p, m);
    float factor = (p / (1.0f + p)) * rsqrtf(p + 1e-8f);
    xv = make_float2(ax * factor, ay * factor);
    *(float2*)(X + (size_t)node * 128 + 2 * l) = xv;
    float2 wa = *(const float2*)(watt + 2 * l);
    att = xv.x * wa.x + xv.y * wa.y;
#pragma unroll
    for (int m = 1; m < 64; m <<= 1) att += __shfl_xor(att, m);
    g = batch[node];
  }
  if (valid) {
    int fb = 2 * l;
    if (g == g0) {
      atomicAdd(&l_ws[fb + 0], att * xv.x);
      atomicAdd(&l_ws[fb + 1], att * xv.y);
      atomicAdd(&l_ms[fb + 0], xv.x);
      atomicAdd(&l_ms[fb + 1], xv.y);
      atomicMax(&l_mx[fb + 0], encf(xv.x));
      atomicMax(&l_mx[fb + 1], encf(xv.y));
    } else {  // rare: graph boundary inside block
      int base = g * 128 + fb;
      atomicAdd(wsum + base + 0, att * xv.x);
      atomicAdd(wsum + base + 1, att * xv.y);
      atomicAdd(msum + base + 0, xv.x);
      atomicAdd(msum + base + 1, xv.y);
      atomicMax(maxenc + base + 0, encf(xv.x));
      atomicMax(maxenc + base + 1, encf(xv.y));
    }
  }
  __syncthreads();
  if (t < 128) {
    int base = g0 * 128 + t;
    atomicAdd(wsum + base, l_ws[t]);
    atomicAdd(msum + base, l_ms[t]);
    unsigned u = l_mx[t];
    if (u) atomicMax(maxenc + base, u);
  }
}

// ---------- MLP head + log_softmax, one block per graph ----------
__global__ __launch_bounds__(128) void k_head(const float* __restrict__ wsum,
                                              const float* __restrict__ msum,
                                              const unsigned* __restrict__ maxenc,
                                              const float* __restrict__ countsf,
                                              const float* __restrict__ l1w,
                                              const float* __restrict__ l1b,
                                              const float* __restrict__ l2w,
                                              const float* __restrict__ l2b,
                                              float* __restrict__ out) {
  int g = blockIdx.x, t = threadIdx.x;
  __shared__ float rep[384];
  __shared__ float h1[128];
  __shared__ float lg[NCLS];
  float invc = 1.0f / countsf[g];
  rep[t] = wsum[g * 128 + t];
  rep[128 + t] = msum[g * 128 + t] * invc;
  rep[256 + t] = decf(maxenc[g * 128 + t]) +
                 decf(maxenc[NGRAPH * 128 + g * 128 + t]) +
                 decf(maxenc[2 * NGRAPH * 128 + g * 128 + t]);
  __syncthreads();
  float acc = l1b[t];
  for (int k = 0; k < 384; k++) acc = fmaf(rep[k], l1w[k * 128 + t], acc);
  h1[t] = fmaxf(acc, 0.f);
  __syncthreads();
  if (t < NCLS) {
    float a = l2b[t];
    for (int j = 0; j < 128; j++) a = fmaf(h1[j], l2w[j * NCLS + t], a);
    lg[t] = a;
  }
  __syncthreads();
  if (t < NCLS) {
    float m = lg[0];
    for (int c = 1; c < NCLS; c++) m = fmaxf(m, lg[c]);
    float s = 0.f;
    for (int c = 0; c < NCLS; c++) s += expf(lg[c] - m);
    out[g * NCLS + t] = lg[t] - m - logf(s);
  }
}

extern "C" void kernel_launch(void* const* d_in, const int* in_sizes, int n_in,
                              void* d_out, int out_size, void* d_ws, size_t ws_size,
                              hipStream_t stream) {
  const float* x      = (const float*)d_in[0];
  const int* edge     = (const int*)d_in[1];
  const int* batch    = (const int*)d_in[2];
  const float* gamma  = (const float*)d_in[3];
  const float* beta   = (const float*)d_in[4];
  const float* gcn_w  = (const float*)d_in[5];
  const float* gcn_b  = (const float*)d_in[6];
  const float* w_att  = (const float*)d_in[7];
  const float* l1w    = (const float*)d_in[8];
  const float* l1b    = (const float*)d_in[9];
  const float* l2w    = (const float*)d_in[10];
  const float* l2b    = (const float*)d_in[11];
  float* out          = (float*)d_out;

  const int N = in_sizes[0] / FDIM;   // 50000
  const int E = in_sizes[1] / 2;      // 640000
  const int* esrc = edge;
  const int* edst = edge + E;

  char* w = (char*)d_ws;
  size_t off = 0;
  auto alloc = [&](size_t bytes) {
    void* p = (void*)(w + off);
    off += (bytes + 1023) & ~(size_t)1023;
    return p;
  };
  float* X  = (float*)alloc((size_t)N * FDIM * 4);
  __half* H = (__half*)alloc((size_t)N * FDIM * 2);
  // zero zone start
  size_t zoff = off;
  int* degcnt      = (int*)alloc((size_t)N * CSTRIDE * 4);   // 1 counter per cache line
  int* cursor      = (int*)alloc((size_t)N * CSTRIDE * 4);   // 1 counter per cache line
  int* gstart      = (int*)alloc(NGRAPH * 4);
  int* gend        = (int*)alloc(NGRAPH * 4);
  float* wsum      = (float*)alloc(NGRAPH * FDIM * 4);
  float* msum      = (float*)alloc(NGRAPH * FDIM * 4);
  unsigned* maxenc = (unsigned*)alloc((size_t)3 * NGRAPH * FDIM * 4);  // per-layer
  size_t zbytes = off - zoff;
  // non-zeroed
  float* partS    = (float*)alloc((size_t)STATS_BLOCKS * FDIM * 4);
  float* partQ    = (float*)alloc((size_t)STATS_BLOCKS * FDIM * 4);
  int* deg_packed = (int*)alloc((size_t)N * 4);
  float* dinv     = (float*)alloc((size_t)N * 4);
  float* countsf  = (float*)alloc(NGRAPH * 4);
  float* aff_a    = (float*)alloc(FDIM * 4);
  float* aff_b    = (float*)alloc(FDIM * 4);
  int* incl       = (int*)alloc((size_t)N * 4);
  int* bsum       = (int*)alloc(1024);
  int* row_start  = (int*)alloc((size_t)N * 4);
  int2* ew        = (int2*)alloc((size_t)E * 8);
  (void)ws_size; (void)n_in; (void)out_size;

  hipMemsetAsync(w + zoff, 0, zbytes, stream);

  const int nbN = (N + 255) / 256;
  const int nbE = (E + 255) / 256;
  const int total4 = N * FDIM / 4;

  k_stats_deg<<<STATS_BLOCKS + nbE, 256, 0, stream>>>(x, partS, partQ, total4, esrc,
                                                      edst, degcnt, batch, gstart, gend,
                                                      E, N);
  k_finalize_pre<<<nbN, 256, 0, stream>>>(degcnt, deg_packed, dinv, gstart, gend,
                                          countsf, partS, partQ, gamma, beta,
                                          aff_a, aff_b, N);
  k_scan1<<<nbN, 256, 0, stream>>>(deg_packed, incl, bsum, N);
  k_scan2<<<1, 256, 0, stream>>>(bsum, nbN);
  k_scan3<<<nbN, 256, 0, stream>>>(incl, deg_packed, bsum, row_start, N);
  k_csr_fill<<<nbE, 256, 0, stream>>>(esrc, edst, row_start, cursor, dinv, ew, E);

  const int gemmBlocks = (N + 63) / 64;
  const int aggBlocks = (N + AGG_NODES - 1) / AGG_NODES;
  for (int layer = 0; layer < 3; layer++) {
    if (layer == 0)
      k_gemm<1><<<gemmBlocks, 256, 0, stream>>>(x, gcn_w, aff_a, aff_b, H, N);
    else
      k_gemm<0><<<gemmBlocks, 256, 0, stream>>>(X, gcn_w + (size_t)layer * FDIM * FDIM,
                                                aff_a, aff_b, H, N);
    k_agg_squash<<<aggBlocks, 512, 0, stream>>>((const __half2*)H, row_start, deg_packed,
                                                ew, gcn_b + layer * FDIM,
                                                w_att + layer * FDIM, batch, dinv, X,
                                                wsum, msum,
                                                maxenc + (size_t)layer * NGRAPH * FDIM, N);
  }
  k_head<<<NGRAPH, 128, 0, stream>>>(wsum, msum, maxenc, countsf, l1w, l1b, l2w, l2b, out);
}

// Round 7
// 534.221 us; speedup vs baseline: 1.1404x; 1.0066x over previous
//
#include <hip/hip_runtime.h>
#include <hip/hip_fp16.h>

#define FDIM 128
#define NGRAPH 256
#define NCLS 10
#define AGG_NODES 8     // nodes per block in k_agg_squash (512 threads = 8 waves)
#define STATS_BLOCKS 256
#define CSTRIDE 16      // ints per counter slot (one 64B line) — kills per-line atomic serialization

__device__ __forceinline__ unsigned encf(float f) {
  unsigned b = __float_as_uint(f);
  return (b & 0x80000000u) ? ~b : (b | 0x80000000u);
}
__device__ __forceinline__ float decf(unsigned u) {
  if (u == 0u) return 0.f;  // empty segment -> 0 (matches isfinite->0)
  return (u & 0x80000000u) ? __uint_as_float(u & 0x7FFFFFFFu) : __uint_as_float(~u);
}

// ---------- BN partial sums (blocks 0..255, no atomics) + degree (spread atomics)
// ---------- + graph segment boundaries from sorted batch (blocks 256+) ----------
__global__ __launch_bounds__(256) void k_stats_deg(const float* __restrict__ x,
                                                   float* __restrict__ partS,
                                                   float* __restrict__ partQ, int total4,
                                                   const int* __restrict__ src,
                                                   const int* __restrict__ dst,
                                                   int* __restrict__ degcnt,
                                                   const int* __restrict__ batch,
                                                   int* __restrict__ gstart,
                                                   int* __restrict__ gend, int E, int N) {
  int t = threadIdx.x;
  if (blockIdx.x >= STATS_BLOCKS) {
    int e = (blockIdx.x - STATS_BLOCKS) * 256 + t;
    if (e < E) {
      int s = src[e], d = dst[e];
      if (s != d) atomicAdd(degcnt + (size_t)d * CSTRIDE, 1);
    }
    if (e < N) {
      int b = batch[e];
      if (e == 0 || batch[e - 1] != b) gstart[b] = e;       // plain stores, ~256 total
      if (e == N - 1) gend[b] = N;
      else if (batch[e + 1] != b) gend[b] = e + 1;
    }
    return;
  }
  __shared__ float ss[1024];
  __shared__ float sq[1024];
  float s0 = 0, s1 = 0, s2 = 0, s3 = 0, q0 = 0, q1 = 0, q2 = 0, q3 = 0;
  for (int i = blockIdx.x * 256 + t; i < total4; i += STATS_BLOCKS * 256) {
    float4 v = ((const float4*)x)[i];
    s0 += v.x; q0 += v.x * v.x;
    s1 += v.y; q1 += v.y * v.y;
    s2 += v.z; q2 += v.z * v.z;
    s3 += v.w; q3 += v.w * v.w;
  }
  int fb = (t & 31) * 4, slot = t >> 5;
  ss[slot * 128 + fb + 0] = s0; ss[slot * 128 + fb + 1] = s1;
  ss[slot * 128 + fb + 2] = s2; ss[slot * 128 + fb + 3] = s3;
  sq[slot * 128 + fb + 0] = q0; sq[slot * 128 + fb + 1] = q1;
  sq[slot * 128 + fb + 2] = q2; sq[slot * 128 + fb + 3] = q3;
  __syncthreads();
  if (t < 128) {
    float a = 0, b = 0;
    for (int s = 0; s < 8; s++) { a += ss[s * 128 + t]; b += sq[s * 128 + t]; }
    partS[blockIdx.x * 128 + t] = a;
    partQ[blockIdx.x * 128 + t] = b;
  }
}

// ---------- fused: finalize (dinv, counts, BN affine) + scan1 block-scan of deg ----------
__global__ __launch_bounds__(256) void k_finalize_scan(const int* __restrict__ degcnt,
                                                       int* __restrict__ deg_packed,
                                                       float* __restrict__ dinv,
                                                       const int* __restrict__ gstart,
                                                       const int* __restrict__ gend,
                                                       float* __restrict__ countsf,
                                                       const float* __restrict__ partS,
                                                       const float* __restrict__ partQ,
                                                       const float* __restrict__ gamma,
                                                       const float* __restrict__ beta,
                                                       float* __restrict__ aff_a,
                                                       float* __restrict__ aff_b,
                                                       int* __restrict__ incl,
                                                       int* __restrict__ bsum, int N) {
  __shared__ int s[256];
  int t = threadIdx.x;
  int i = blockIdx.x * 256 + t;
  int d = 0;
  if (i < N) {
    d = degcnt[(size_t)i * CSTRIDE];
    deg_packed[i] = d;
    dinv[i] = rsqrtf(1.0f + (float)d);
  }
  if (i < NGRAPH) countsf[i] = fmaxf((float)(gend[i] - gstart[i]), 1.0f);
  if (i < FDIM) {
    float a = 0.f, b = 0.f;
    for (int bk = 0; bk < STATS_BLOCKS; bk++) {
      a += partS[bk * 128 + i];
      b += partQ[bk * 128 + i];
    }
    float invN = 1.0f / (float)N;
    float mu = a * invN;
    float var = b * invN - mu * mu;
    float inv = rsqrtf(var + 1e-5f);
    float ga = gamma[i] * inv;
    aff_a[i] = ga;
    aff_b[i] = beta[i] - mu * ga;
  }
  // block-inclusive scan of d
  s[t] = d;
  __syncthreads();
  for (int off = 1; off < 256; off <<= 1) {
    int add = (t >= off) ? s[t - off] : 0;
    __syncthreads();
    s[t] += add;
    __syncthreads();
  }
  if (i < N) incl[i] = s[t];
  if (t == 255) bsum[blockIdx.x] = s[255];
}

__global__ __launch_bounds__(256) void k_scan2(int* __restrict__ bsum, int nb) {
  __shared__ int s[256];
  int t = threadIdx.x;
  int v = (t < nb) ? bsum[t] : 0;
  s[t] = v;
  __syncthreads();
  for (int off = 1; off < 256; off <<= 1) {
    int add = (t >= off) ? s[t - off] : 0;
    __syncthreads();
    s[t] += add;
    __syncthreads();
  }
  if (t < nb) bsum[t] = s[t] - v;  // exclusive
}

__global__ __launch_bounds__(256) void k_scan3(const int* __restrict__ incl,
                                               const int* __restrict__ deg,
                                               const int* __restrict__ bsum,
                                               int* __restrict__ row_start, int N) {
  int i = blockIdx.x * 256 + threadIdx.x;
  if (i < N) row_start[i] = incl[i] - deg[i] + bsum[blockIdx.x];
}

// ---------- fill CSR: packed (src, dinv[src]*dinv[dst]); cursor spread 1/line ----------
__global__ __launch_bounds__(256) void k_csr_fill(const int* __restrict__ src,
                                                  const int* __restrict__ dst,
                                                  const int* __restrict__ row_start,
                                                  int* __restrict__ cursor,
                                                  const float* __restrict__ dinv,
                                                  int2* __restrict__ ew, int E) {
  int e = blockIdx.x * 256 + threadIdx.x;
  if (e < E) {
    int s = src[e], d = dst[e];
    if (s != d) {
      int p = row_start[d] + atomicAdd(cursor + (size_t)d * CSTRIDE, 1);
      ew[p] = make_int2(s, __float_as_int(dinv[s] * dinv[d]));
    }
  }
}

// ---------- GEMM: H = X @ W  (N x 128 @ 128 x 128), W in LDS; H stored fp16 ----------
template <int AFFINE>
__global__ __launch_bounds__(256) void k_gemm(const float* __restrict__ Xin,
                                              const float* __restrict__ W,
                                              const float* __restrict__ aff_a,
                                              const float* __restrict__ aff_b,
                                              __half* __restrict__ Hout, int N) {
  __shared__ float sW[128 * 128];
  __shared__ float sA[128];
  __shared__ float sB[128];
  int t = threadIdx.x;
#pragma unroll
  for (int i = 0; i < 16; i++) {
    int idx = t * 4 + i * 1024;
    *(float4*)(sW + idx) = *(const float4*)(W + idx);
  }
  if (AFFINE && t < 128) { sA[t] = aff_a[t]; sB[t] = aff_b[t]; }
  __syncthreads();
  int tx = t & 31, ty = t >> 5;
  int nodeBase = blockIdx.x * 64 + ty * 8;
  if (nodeBase >= N) return;  // after the only __syncthreads
  int nidx[8];
#pragma unroll
  for (int i = 0; i < 8; i++) nidx[i] = min(nodeBase + i, N - 1);
  float acc[8][4];
#pragma unroll
  for (int i = 0; i < 8; i++) { acc[i][0] = acc[i][1] = acc[i][2] = acc[i][3] = 0.f; }
#pragma unroll 2
  for (int k = 0; k < 128; k += 4) {
    float4 b0 = *(const float4*)(sW + (k + 0) * 128 + tx * 4);
    float4 b1 = *(const float4*)(sW + (k + 1) * 128 + tx * 4);
    float4 b2 = *(const float4*)(sW + (k + 2) * 128 + tx * 4);
    float4 b3 = *(const float4*)(sW + (k + 3) * 128 + tx * 4);
    float4 va, vb;
    if (AFFINE) { va = *(const float4*)(sA + k); vb = *(const float4*)(sB + k); }
#pragma unroll
    for (int i = 0; i < 8; i++) {
      float4 a = *(const float4*)(Xin + (long)nidx[i] * 128 + k);
      if (AFFINE) {
        a.x = fmaf(a.x, va.x, vb.x);
        a.y = fmaf(a.y, va.y, vb.y);
        a.z = fmaf(a.z, va.z, vb.z);
        a.w = fmaf(a.w, va.w, vb.w);
      }
      acc[i][0] = fmaf(a.w, b3.x, fmaf(a.z, b2.x, fmaf(a.y, b1.x, fmaf(a.x, b0.x, acc[i][0]))));
      acc[i][1] = fmaf(a.w, b3.y, fmaf(a.z, b2.y, fmaf(a.y, b1.y, fmaf(a.x, b0.y, acc[i][1]))));
      acc[i][2] = fmaf(a.w, b3.z, fmaf(a.z, b2.z, fmaf(a.y, b1.z, fmaf(a.x, b0.z, acc[i][2]))));
      acc[i][3] = fmaf(a.w, b3.w, fmaf(a.z, b2.w, fmaf(a.y, b1.w, fmaf(a.x, b0.w, acc[i][3]))));
    }
  }
#pragma unroll
  for (int i = 0; i < 8; i++) {
    int node = nodeBase + i;
    if (node < N) {
      __half2 p0 = __floats2half2_rn(acc[i][0], acc[i][1]);
      __half2 p1 = __floats2half2_rn(acc[i][2], acc[i][3]);
      uint2 st;
      st.x = *(unsigned*)&p0;
      st.y = *(unsigned*)&p1;
      *(uint2*)(Hout + (size_t)node * 128 + tx * 4) = st;
    }
  }
}

// ---------- fused: CSR aggregate + bias + squash + attention + graph scatter ----------
// One wave per dst node; lane l owns features 2l,2l+1 (one half2 = 4B per lane).
// Edge loop PADDED to ILP-4: ew read unconditionally (+4 slack entries), weight
// and index masked by wave-uniform j+u<cnt (scalar cselect). No tail loop.
__global__ __launch_bounds__(512) void k_agg_squash(const __half2* __restrict__ H,
                                                    const int* __restrict__ row_start,
                                                    const int* __restrict__ deg,
                                                    const int2* __restrict__ ew,
                                                    const float* __restrict__ bias,
                                                    const float* __restrict__ watt,
                                                    const int* __restrict__ batch,
                                                    const float* __restrict__ dinv,
                                                    float* __restrict__ X,
                                                    float* __restrict__ wsum,
                                                    float* __restrict__ msum,
                                                    unsigned* __restrict__ maxenc, int N) {
  __shared__ float l_ws[128];
  __shared__ float l_ms[128];
  __shared__ unsigned l_mx[128];
  int t = threadIdx.x;
  if (t < 128) { l_ws[t] = 0.f; l_ms[t] = 0.f; l_mx[t] = 0u; }
  __syncthreads();

  int wv = t >> 6, l = t & 63;
  int node = blockIdx.x * AGG_NODES + wv;
  int g0 = batch[blockIdx.x * AGG_NODES];
  bool valid = node < N;
  float2 xv = make_float2(0.f, 0.f);
  float att = 0.f;
  int g = g0;
  if (valid) {
    float dn = dinv[node];
    float2 h0 = __half22float2(H[(size_t)node * 64 + l]);
    float2 bb = *(const float2*)(bias + 2 * l);
    float sl = dn * dn;
    float a0x = fmaf(sl, h0.x, bb.x), a0y = fmaf(sl, h0.y, bb.y);
    float a1x = 0.f, a1y = 0.f, a2x = 0.f, a2y = 0.f, a3x = 0.f, a3y = 0.f;
    int st = row_start[node], cnt = deg[node];
    for (int j = 0; j < cnt; j += 4) {
      int2 e0 = ew[st + j + 0];
      int2 e1 = ew[st + j + 1];
      int2 e2 = ew[st + j + 2];
      int2 e3 = ew[st + j + 3];
      bool v1 = (j + 1 < cnt), v2 = (j + 2 < cnt), v3 = (j + 3 < cnt);
      int s0 = e0.x;
      int s1 = v1 ? e1.x : 0;
      int s2 = v2 ? e2.x : 0;
      int s3 = v3 ? e3.x : 0;
      float w0 = __int_as_float(e0.y);
      float w1 = v1 ? __int_as_float(e1.y) : 0.f;
      float w2 = v2 ? __int_as_float(e2.y) : 0.f;
      float w3 = v3 ? __int_as_float(e3.y) : 0.f;
      float2 r0 = __half22float2(H[(size_t)s0 * 64 + l]);
      float2 r1 = __half22float2(H[(size_t)s1 * 64 + l]);
      float2 r2 = __half22float2(H[(size_t)s2 * 64 + l]);
      float2 r3 = __half22float2(H[(size_t)s3 * 64 + l]);
      a0x = fmaf(w0, r0.x, a0x); a0y = fmaf(w0, r0.y, a0y);
      a1x = fmaf(w1, r1.x, a1x); a1y = fmaf(w1, r1.y, a1y);
      a2x = fmaf(w2, r2.x, a2x); a2y = fmaf(w2, r2.y, a2y);
      a3x = fmaf(w3, r3.x, a3x); a3y = fmaf(w3, r3.y, a3y);
    }
    float ax = (a0x + a1x) + (a2x + a3x);
    float ay = (a0y + a1y) + (a2y + a3y);
    float p = ax * ax + ay * ay;
#pragma unroll
    for (int m = 1; m < 64; m <<= 1) p += __shfl_xor(p, m);
    float factor = (p / (1.0f + p)) * rsqrtf(p + 1e-8f);
    xv = make_float2(ax * factor, ay * factor);
    *(float2*)(X + (size_t)node * 128 + 2 * l) = xv;
    float2 wa = *(const float2*)(watt + 2 * l);
    att = xv.x * wa.x + xv.y * wa.y;
#pragma unroll
    for (int m = 1; m < 64; m <<= 1) att += __shfl_xor(att, m);
    g = batch[node];
  }
  if (valid) {
    int fb = 2 * l;
    if (g == g0) {
      atomicAdd(&l_ws[fb + 0], att * xv.x);
      atomicAdd(&l_ws[fb + 1], att * xv.y);
      atomicAdd(&l_ms[fb + 0], xv.x);
      atomicAdd(&l_ms[fb + 1], xv.y);
      atomicMax(&l_mx[fb + 0], encf(xv.x));
      atomicMax(&l_mx[fb + 1], encf(xv.y));
    } else {  // rare: graph boundary inside block
      int base = g * 128 + fb;
      atomicAdd(wsum + base + 0, att * xv.x);
      atomicAdd(wsum + base + 1, att * xv.y);
      atomicAdd(msum + base + 0, xv.x);
      atomicAdd(msum + base + 1, xv.y);
      atomicMax(maxenc + base + 0, encf(xv.x));
      atomicMax(maxenc + base + 1, encf(xv.y));
    }
  }
  __syncthreads();
  if (t < 128) {
    int base = g0 * 128 + t;
    atomicAdd(wsum + base, l_ws[t]);
    atomicAdd(msum + base, l_ms[t]);
    unsigned u = l_mx[t];
    if (u) atomicMax(maxenc + base, u);
  }
}

// ---------- MLP head + log_softmax, one block per graph ----------
__global__ __launch_bounds__(128) void k_head(const float* __restrict__ wsum,
                                              const float* __restrict__ msum,
                                              const unsigned* __restrict__ maxenc,
                                              const float* __restrict__ countsf,
                                              const float* __restrict__ l1w,
                                              const float* __restrict__ l1b,
                                              const float* __restrict__ l2w,
                                              const float* __restrict__ l2b,
                                              float* __restrict__ out) {
  int g = blockIdx.x, t = threadIdx.x;
  __shared__ float rep[384];
  __shared__ float h1[128];
  __shared__ float lg[NCLS];
  float invc = 1.0f / countsf[g];
  rep[t] = wsum[g * 128 + t];
  rep[128 + t] = msum[g * 128 + t] * invc;
  rep[256 + t] = decf(maxenc[g * 128 + t]) +
                 decf(maxenc[NGRAPH * 128 + g * 128 + t]) +
                 decf(maxenc[2 * NGRAPH * 128 + g * 128 + t]);
  __syncthreads();
  float acc = l1b[t];
  for (int k = 0; k < 384; k++) acc = fmaf(rep[k], l1w[k * 128 + t], acc);
  h1[t] = fmaxf(acc, 0.f);
  __syncthreads();
  if (t < NCLS) {
    float a = l2b[t];
    for (int j = 0; j < 128; j++) a = fmaf(h1[j], l2w[j * NCLS + t], a);
    lg[t] = a;
  }
  __syncthreads();
  if (t < NCLS) {
    float m = lg[0];
    for (int c = 1; c < NCLS; c++) m = fmaxf(m, lg[c]);
    float s = 0.f;
    for (int c = 0; c < NCLS; c++) s += expf(lg[c] - m);
    out[g * NCLS + t] = lg[t] - m - logf(s);
  }
}

extern "C" void kernel_launch(void* const* d_in, const int* in_sizes, int n_in,
                              void* d_out, int out_size, void* d_ws, size_t ws_size,
                              hipStream_t stream) {
  const float* x      = (const float*)d_in[0];
  const int* edge     = (const int*)d_in[1];
  const int* batch    = (const int*)d_in[2];
  const float* gamma  = (const float*)d_in[3];
  const float* beta   = (const float*)d_in[4];
  const float* gcn_w  = (const float*)d_in[5];
  const float* gcn_b  = (const float*)d_in[6];
  const float* w_att  = (const float*)d_in[7];
  const float* l1w    = (const float*)d_in[8];
  const float* l1b    = (const float*)d_in[9];
  const float* l2w    = (const float*)d_in[10];
  const float* l2b    = (const float*)d_in[11];
  float* out          = (float*)d_out;

  const int N = in_sizes[0] / FDIM;   // 50000
  const int E = in_sizes[1] / 2;      // 640000
  const int* esrc = edge;
  const int* edst = edge + E;

  char* w = (char*)d_ws;
  size_t off = 0;
  auto alloc = [&](size_t bytes) {
    void* p = (void*)(w + off);
    off += (bytes + 1023) & ~(size_t)1023;
    return p;
  };
  float* X  = (float*)alloc((size_t)N * FDIM * 4);
  __half* H = (__half*)alloc((size_t)N * FDIM * 2);
  // zero zone start
  size_t zoff = off;
  int* degcnt      = (int*)alloc((size_t)N * CSTRIDE * 4);   // 1 counter per cache line
  int* cursor      = (int*)alloc((size_t)N * CSTRIDE * 4);   // 1 counter per cache line
  int* gstart      = (int*)alloc(NGRAPH * 4);
  int* gend        = (int*)alloc(NGRAPH * 4);
  float* wsum      = (float*)alloc(NGRAPH * FDIM * 4);
  float* msum      = (float*)alloc(NGRAPH * FDIM * 4);
  unsigned* maxenc = (unsigned*)alloc((size_t)3 * NGRAPH * FDIM * 4);  // per-layer
  size_t zbytes = off - zoff;
  // non-zeroed
  float* partS    = (float*)alloc((size_t)STATS_BLOCKS * FDIM * 4);
  float* partQ    = (float*)alloc((size_t)STATS_BLOCKS * FDIM * 4);
  int* deg_packed = (int*)alloc((size_t)N * 4);
  float* dinv     = (float*)alloc((size_t)N * 4);
  float* countsf  = (float*)alloc(NGRAPH * 4);
  float* aff_a    = (float*)alloc(FDIM * 4);
  float* aff_b    = (float*)alloc(FDIM * 4);
  int* incl       = (int*)alloc((size_t)N * 4);
  int* bsum       = (int*)alloc(1024);
  int* row_start  = (int*)alloc((size_t)N * 4);
  int2* ew        = (int2*)alloc(((size_t)E + 4) * 8);  // +4 slack for padded reads
  (void)ws_size; (void)n_in; (void)out_size;

  hipMemsetAsync(w + zoff, 0, zbytes, stream);

  const int nbN = (N + 255) / 256;
  const int nbE = (E + 255) / 256;
  const int total4 = N * FDIM / 4;

  k_stats_deg<<<STATS_BLOCKS + nbE, 256, 0, stream>>>(x, partS, partQ, total4, esrc,
                                                      edst, degcnt, batch, gstart, gend,
                                                      E, N);
  k_finalize_scan<<<nbN, 256, 0, stream>>>(degcnt, deg_packed, dinv, gstart, gend,
                                           countsf, partS, partQ, gamma, beta,
                                           aff_a, aff_b, incl, bsum, N);
  k_scan2<<<1, 256, 0, stream>>>(bsum, nbN);
  k_scan3<<<nbN, 256, 0, stream>>>(incl, deg_packed, bsum, row_start, N);
  k_csr_fill<<<nbE, 256, 0, stream>>>(esrc, edst, row_start, cursor, dinv, ew, E);

  const int gemmBlocks = (N + 63) / 64;
  const int aggBlocks = (N + AGG_NODES - 1) / AGG_NODES;
  for (int layer = 0; layer < 3; layer++) {
    if (layer == 0)
      k_gemm<1><<<gemmBlocks, 256, 0, stream>>>(x, gcn_w, aff_a, aff_b, H, N);
    else
      k_gemm<0><<<gemmBlocks, 256, 0, stream>>>(X, gcn_w + (size_t)layer * FDIM * FDIM,
                                                aff_a, aff_b, H, N);
    k_agg_squash<<<aggBlocks, 512, 0, stream>>>((const __half2*)H, row_start, deg_packed,
                                                ew, gcn_b + layer * FDIM,
                                                w_att + layer * FDIM, batch, dinv, X,
                                                wsum, msum,
                                                maxenc + (size_t)layer * NGRAPH * FDIM, N);
  }
  k_head<<<NGRAPH, 128, 0, stream>>>(wsum, msum, maxenc, countsf, l1w, l1b, l2w, l2b, out);
}